// Round 1
// baseline (229.611 us; speedup 1.0000x reference)
//
#include <hip/hip_runtime.h>

typedef __bf16 bf16;
typedef __bf16 bf16x8 __attribute__((ext_vector_type(8)));
typedef float f32x4 __attribute__((ext_vector_type(4)));
typedef float f32x16 __attribute__((ext_vector_type(16)));
typedef unsigned int u32;
typedef u32 u32x2 __attribute__((ext_vector_type(2)));
typedef u32 u32x4 __attribute__((ext_vector_type(4)));

#define MFMA16(A,B,C) __builtin_amdgcn_mfma_f32_16x16x32_bf16(A,B,C,0,0,0)
#define MFMA32(A,B,C) __builtin_amdgcn_mfma_f32_32x32x16_bf16(A,B,C,0,0,0)

static __device__ __forceinline__ u32 cvt_pk_bf16(float lo, float hi) {
    u32 r;
    asm("v_cvt_pk_bf16_f32 %0, %1, %2" : "=v"(r) : "v"(lo), "v"(hi));
    return r;
}
// After: a = [a.lo | b.lo], b = [a.hi | b.hi]  (swaps a's upper 32 lanes with b's lower 32)
static __device__ __forceinline__ void permlane32_swap(u32& a, u32& b) {
    asm("v_permlane32_swap_b32 %0, %1" : "+v"(a), "+v"(b));
}

// ---------------------------------------------------------------------------
// Kernel 1: BN + three projections (bf16 MFMA GEMM, K=256, N=128 each).
// A = input rows (b,n) x channels c (BN applied on the fly), B = weights.
// Output scattered into K/Q/V arrays, layout (b, head, n, d) bf16, d=64.
// Q gets the 1/sqrt(64) = 0.125 scale folded in (exact in bf16).
// MODE 0: rgb->kq1 (d base 0), MODE 1: dsm->kq2 (d base 32), MODE 2: fusion->v
// ---------------------------------------------------------------------------
template<int MODE>
static __device__ __forceinline__ void gemm_prep(
    const float* __restrict__ X, const float* __restrict__ W,
    const float* __restrict__ bias,
    const float* __restrict__ sInv, const float* __restrict__ sBeta,
    int b, int n0, int l15, int g, int jb,
    bf16* __restrict__ Ko, bf16* __restrict__ Qo, bf16* __restrict__ Vo)
{
    const f32x4 z4 = {0.f, 0.f, 0.f, 0.f};
    f32x4 acc[4][2];
#pragma unroll
    for (int i = 0; i < 4; ++i) { acc[i][0] = z4; acc[i][1] = z4; }

    const float* Xb = X + b * 256 * 4096;

    for (int ks = 0; ks < 8; ++ks) {
        const int c0 = ks * 32 + g * 8;
        f32x4 iv0 = z4, iv1 = z4, bt0 = z4, bt1 = z4;
        if constexpr (MODE < 2) {
            iv0 = *(const f32x4*)(sInv + c0);  iv1 = *(const f32x4*)(sInv + c0 + 4);
            bt0 = *(const f32x4*)(sBeta + c0); bt1 = *(const f32x4*)(sBeta + c0 + 4);
        }
        bf16x8 af[4];
#pragma unroll
        for (int rt = 0; rt < 4; ++rt) {
            const int n = n0 + rt * 16 + l15;
            const float* xp = Xb + c0 * 4096 + n;
#pragma unroll
            for (int jj = 0; jj < 4; ++jj) {
                float x0 = xp[jj * 4096];
                float x1 = xp[(jj + 4) * 4096];
                if constexpr (MODE < 2) {
                    x0 = fmaf(x0, iv0[jj], bt0[jj]);
                    x1 = fmaf(x1, iv1[jj], bt1[jj]);
                }
                af[rt][jj]     = (bf16)x0;
                af[rt][jj + 4] = (bf16)x1;
            }
        }
#pragma unroll
        for (int ci = 0; ci < 2; ++ci) {
            const int j = jb + ci * 16 + l15;
            const f32x4* wp = (const f32x4*)(W + j * 256 + c0);
            const f32x4 w0 = wp[0], w1 = wp[1];
            bf16x8 bv;
#pragma unroll
            for (int jj = 0; jj < 4; ++jj) { bv[jj] = (bf16)w0[jj]; bv[jj + 4] = (bf16)w1[jj]; }
#pragma unroll
            for (int rt = 0; rt < 4; ++rt)
                acc[rt][ci] = MFMA16(af[rt], bv, acc[rt][ci]);
        }
    }

    // D layout (16x16x32): col = lane&15 (= output j), row = (lane>>4)*4 + r (= n offset)
#pragma unroll
    for (int ci = 0; ci < 2; ++ci) {
        const int j = jb + ci * 16 + l15;
        const float bs = bias[j];
#pragma unroll
        for (int rt = 0; rt < 4; ++rt) {
#pragma unroll
            for (int r = 0; r < 4; ++r) {
                const int n = n0 + rt * 16 + g * 4 + r;
                float v = acc[rt][ci][r] + bs;
                if constexpr (MODE == 2) {
                    const int head = j >> 6, d = j & 63;
                    Vo[((b * 2 + head) * 4096 + n) * 64 + d] = (bf16)v;
                } else {
                    const int seg = j >> 5;             // 0:K h0, 1:Q h0, 2:K h1, 3:Q h1
                    const int head = seg >> 1;
                    const int d = (j & 31) + (MODE == 1 ? 32 : 0);
                    if (seg & 1)
                        Qo[((b * 2 + head) * 4096 + n) * 64 + d] = (bf16)(v * 0.125f);
                    else
                        Ko[((b * 2 + head) * 4096 + n) * 64 + d] = (bf16)v;
                }
            }
        }
    }
}

__global__ __launch_bounds__(256) void prep_kernel(
    const float* __restrict__ fus, const float* __restrict__ rgb, const float* __restrict__ dsm,
    const float* __restrict__ bn1w, const float* __restrict__ bn1b,
    const float* __restrict__ bn1m, const float* __restrict__ bn1v,
    const float* __restrict__ bn2w, const float* __restrict__ bn2b,
    const float* __restrict__ bn2m, const float* __restrict__ bn2v,
    const float* __restrict__ kq1w, const float* __restrict__ kq1b,
    const float* __restrict__ kq2w, const float* __restrict__ kq2b,
    const float* __restrict__ vw,  const float* __restrict__ vb,
    bf16* __restrict__ Ko, bf16* __restrict__ Qo, bf16* __restrict__ Vo)
{
    __shared__ float sInv1[256], sBeta1[256], sInv2[256], sBeta2[256];
    const int t = threadIdx.x;
    {
        float iv1 = bn1w[t] * rsqrtf(bn1v[t] + 1e-5f);
        sInv1[t] = iv1; sBeta1[t] = bn1b[t] - bn1m[t] * iv1;
        float iv2 = bn2w[t] * rsqrtf(bn2v[t] + 1e-5f);
        sInv2[t] = iv2; sBeta2[t] = bn2b[t] - bn2m[t] * iv2;
    }
    __syncthreads();
    const int wg = blockIdx.x;
    const int b = wg >> 6, n0 = (wg & 63) * 64;
    const int lane = t & 63, w = t >> 6;
    const int l15 = lane & 15, g = lane >> 4;
    const int jb = w * 32;           // each wave owns 32 output cols, all 64 rows

    gemm_prep<0>(rgb, kq1w, kq1b, sInv1, sBeta1, b, n0, l15, g, jb, Ko, Qo, Vo);
    gemm_prep<1>(dsm, kq2w, kq2b, sInv2, sBeta2, b, n0, l15, g, jb, Ko, Qo, Vo);
    gemm_prep<2>(fus, vw,   vb,   nullptr, nullptr, b, n0, l15, g, jb, Ko, Qo, Vo);
}

// ---------------------------------------------------------------------------
// Kernel 2: flash attention, 32x32 MFMA, swapped-operand structure.
// Per wg: 2 warps x 32 q-rows, loop over 64-key blocks.
// S^T = mfma32(K_frag, Q_frag): lane owns q-row (lane&31); its P row lives in
// 32 f32 regs with key = 32*kt + (r&3) + 8*(r>>2) + 4*hi   (hi = lane>>5).
// Softmax fully in-lane (+ one shfl_xor(32) merge with the partner lane).
// P -> bf16 fragments via cvt_pk + permlane32_swap.
// O^T = mfma32(Vt_frag, P_frag): lane keeps its own q-row's O -> per-lane
// rescale/divide, no shuffles. V^T staged in LDS with XOR swizzle.
// ---------------------------------------------------------------------------
__global__ __launch_bounds__(128) void attn_kernel(
    const bf16* __restrict__ Ki, const bf16* __restrict__ Qi,
    const bf16* __restrict__ Vi, bf16* __restrict__ Oo)
{
    __shared__ __align__(16) bf16 sVt[64 * 72];   // [d][key^swz], pad 72 elems/row

    const int id = blockIdx.x;            // 512 wgs
    const int b  = id >> 7;
    const int h  = (id >> 6) & 1;
    const int qt = id & 63;
    const int base = (b * 2 + h) * 4096;
    const int t = threadIdx.x;
    const int lane = t & 63, w = t >> 6;
    const int l31 = lane & 31, hi = lane >> 5;
    const int qrow = qt * 64 + w * 32 + l31;

    bf16x8 qf[4];
    {
        const bf16* qp = Qi + (base + qrow) * 64;
#pragma unroll
        for (int ds = 0; ds < 4; ++ds)
            qf[ds] = *(const bf16x8*)(qp + ds * 16 + hi * 8);
    }

    f32x16 ot[2];
#pragma unroll
    for (int i = 0; i < 16; ++i) { ot[0][i] = 0.f; ot[1][i] = 0.f; }
    float m = -1e30f, lsum = 0.f;

    const bf16* Kb = Ki + base * 64;
    const bf16* Vb = Vi + base * 64;

    bf16x8 vr[4];
#pragma unroll
    for (int i = 0; i < 4; ++i) {
        const int c = t + i * 128;
        vr[i] = *(const bf16x8*)(Vb + (c >> 3) * 64 + (c & 7) * 8);
    }
#pragma unroll
    for (int i = 0; i < 4; ++i) {
        const int c = t + i * 128;
        const int key = c >> 3, d0 = (c & 7) * 8;
#pragma unroll
        for (int jj = 0; jj < 8; ++jj) {
            const int d = d0 + jj;
            sVt[d * 72 + (key ^ (((d >> 3) & 7) << 3))] = vr[i][jj];
        }
    }
    __syncthreads();

    for (int kb = 0; kb < 64; ++kb) {
        if (kb + 1 < 64) {   // prefetch next V block into regs (overlaps compute)
#pragma unroll
            for (int i = 0; i < 4; ++i) {
                const int c = t + i * 128;
                vr[i] = *(const bf16x8*)(Vb + ((kb + 1) * 64 + (c >> 3)) * 64 + (c & 7) * 8);
            }
        }
        // ---- S^T = K . Q^T  (K fragments straight from global; L2/L1-hot) ----
        float p[32];
#pragma unroll
        for (int kt = 0; kt < 2; ++kt) {
            f32x16 acc;
#pragma unroll
            for (int i = 0; i < 16; ++i) acc[i] = 0.f;
#pragma unroll
            for (int ds = 0; ds < 4; ++ds) {
                bf16x8 kf = *(const bf16x8*)(Kb + (kb * 64 + kt * 32 + l31) * 64 + ds * 16 + hi * 8);
                acc = MFMA32(kf, qf[ds], acc);
            }
#pragma unroll
            for (int r = 0; r < 16; ++r) p[kt * 16 + r] = acc[r];
        }
        // ---- online softmax (per-lane; lane pair l,l+32 share the q-row) ----
        float pm[16];
#pragma unroll
        for (int i = 0; i < 16; ++i) pm[i] = fmaxf(p[i], p[i + 16]);
#pragma unroll
        for (int off = 8; off >= 1; off >>= 1)
#pragma unroll
            for (int i = 0; i < off; ++i) pm[i] = fmaxf(pm[i], pm[i + off]);
        const float bm = fmaxf(pm[0], __shfl_xor(pm[0], 32));
        const float mn = fmaxf(m, bm);
        const float cc = __expf(m - mn);
        m = mn;
#pragma unroll
        for (int i = 0; i < 32; ++i) p[i] = __expf(p[i] - mn);
        float ps[16];
#pragma unroll
        for (int i = 0; i < 16; ++i) ps[i] = p[i] + p[i + 16];
#pragma unroll
        for (int off = 8; off >= 1; off >>= 1)
#pragma unroll
            for (int i = 0; i < off; ++i) ps[i] += ps[i + off];
        const float s = ps[0] + __shfl_xor(ps[0], 32);
        lsum = lsum * cc + s;
        ot[0] = ot[0] * cc;
        ot[1] = ot[1] * cc;

        // ---- P -> bf16 fragments: pa[ks] holds P[q][16*ks + 8*hi + j] ----
        bf16x8 pa[4];
#pragma unroll
        for (int ks = 0; ks < 4; ++ks) {
            const int pb = 16 * (ks >> 1) + 8 * (ks & 1);
            u32 wa0 = cvt_pk_bf16(p[pb + 0], p[pb + 1]);
            u32 wa1 = cvt_pk_bf16(p[pb + 2], p[pb + 3]);
            u32 wb0 = cvt_pk_bf16(p[pb + 4], p[pb + 5]);
            u32 wb1 = cvt_pk_bf16(p[pb + 6], p[pb + 7]);
            permlane32_swap(wa0, wb0);
            permlane32_swap(wa1, wb1);
            u32x4 pk; pk[0] = wa0; pk[1] = wa1; pk[2] = wb0; pk[3] = wb1;
            pa[ks] = __builtin_bit_cast(bf16x8, pk);
        }
        // ---- O^T += V^T . P^T ----
#pragma unroll
        for (int dt = 0; dt < 2; ++dt) {
            const int d_ = dt * 32 + l31;
            const int e8 = ((d_ >> 3) & 7) << 3;
#pragma unroll
            for (int ks = 0; ks < 4; ++ks) {
                bf16x8 vt = *(const bf16x8*)(sVt + d_ * 72 + ((ks * 16 + hi * 8) ^ e8));
                ot[dt] = MFMA32(vt, pa[ks], ot[dt]);
            }
        }
        __syncthreads();
        if (kb + 1 < 64) {   // scatter prefetched V into LDS as V^T
#pragma unroll
            for (int i = 0; i < 4; ++i) {
                const int c = t + i * 128;
                const int key = c >> 3, d0 = (c & 7) * 8;
#pragma unroll
                for (int jj = 0; jj < 8; ++jj) {
                    const int d = d0 + jj;
                    sVt[d * 72 + (key ^ (((d >> 3) & 7) << 3))] = vr[i][jj];
                }
            }
        }
        __syncthreads();
    }

    // ---- epilogue: O[q][d] = ot / lsum ; d = 32*dt + (r&3) + 8*(r>>2) + 4*hi
    const float rl = 1.0f / lsum;
    bf16* op = Oo + (b * 4096 + qrow) * 128 + h * 64;
#pragma unroll
    for (int dt = 0; dt < 2; ++dt) {
#pragma unroll
        for (int rq = 0; rq < 4; ++rq) {
            u32 lo  = cvt_pk_bf16(ot[dt][rq * 4 + 0] * rl, ot[dt][rq * 4 + 1] * rl);
            u32 hi2 = cvt_pk_bf16(ot[dt][rq * 4 + 2] * rl, ot[dt][rq * 4 + 3] * rl);
            u32x2 pk; pk[0] = lo; pk[1] = hi2;
            *(u32x2*)(op + dt * 32 + rq * 8 + hi * 4) = pk;
        }
    }
}

// ---------------------------------------------------------------------------
// Kernel 3: out = sigmoid(BN(O @ out_w^T + out_b)) * fusion * gamma + fusion
// Swapped operands: D[c][n] = W . O^T so stores/fusion-loads are n-contiguous.
// ---------------------------------------------------------------------------
__global__ __launch_bounds__(256) void out_kernel(
    const bf16* __restrict__ Oi, const float* __restrict__ outw, const float* __restrict__ outb,
    const float* __restrict__ bnlw, const float* __restrict__ bnlb,
    const float* __restrict__ bnlm, const float* __restrict__ bnlv,
    const float* __restrict__ fus, const float* __restrict__ gamma,
    float* __restrict__ out)
{
    __shared__ float sInv[256], sBeta[256], sOb[256];
    const int t = threadIdx.x;
    {
        float iv = bnlw[t] * rsqrtf(bnlv[t] + 1e-5f);
        sInv[t] = iv; sBeta[t] = bnlb[t] - bnlm[t] * iv; sOb[t] = outb[t];
    }
    __syncthreads();
    const int wg = blockIdx.x;
    const int b = wg >> 6, n0 = (wg & 63) * 64;
    const int lane = t & 63, w = t >> 6, l15 = lane & 15, g = lane >> 4;
    const float gam = gamma[0];

    const f32x4 z4 = {0.f, 0.f, 0.f, 0.f};
    f32x4 acc[4][4];
#pragma unroll
    for (int i = 0; i < 4; ++i)
#pragma unroll
        for (int j = 0; j < 4; ++j) acc[i][j] = z4;

#pragma unroll
    for (int ks = 0; ks < 4; ++ks) {
        const int k0 = ks * 32 + g * 8;
        bf16x8 af[4];
#pragma unroll
        for (int rt = 0; rt < 4; ++rt) {
            const int c = w * 64 + rt * 16 + l15;
            const f32x4* wp = (const f32x4*)(outw + c * 128 + k0);
            const f32x4 w0 = wp[0], w1 = wp[1];
#pragma unroll
            for (int jj = 0; jj < 4; ++jj) { af[rt][jj] = (bf16)w0[jj]; af[rt][jj + 4] = (bf16)w1[jj]; }
        }
#pragma unroll
        for (int ct = 0; ct < 4; ++ct) {
            const int n = n0 + ct * 16 + l15;
            bf16x8 bv = *(const bf16x8*)(Oi + (b * 4096 + n) * 128 + k0);
#pragma unroll
            for (int rt = 0; rt < 4; ++rt)
                acc[rt][ct] = MFMA16(af[rt], bv, acc[rt][ct]);
        }
    }

#pragma unroll
    for (int rt = 0; rt < 4; ++rt) {
#pragma unroll
        for (int r = 0; r < 4; ++r) {
            const int c = w * 64 + rt * 16 + g * 4 + r;
            const float iv = sInv[c], bt = sBeta[c], ob = sOb[c];
            const int rowoff = (b * 256 + c) * 4096;
#pragma unroll
            for (int ct = 0; ct < 4; ++ct) {
                const int n = n0 + ct * 16 + l15;
                const float v  = acc[rt][ct][r] + ob;
                const float bn = fmaf(v, iv, bt);
                const float sg = 1.0f / (1.0f + __expf(-bn));
                const float f  = fus[rowoff + n];
                out[rowoff + n] = f * fmaf(sg, gam, 1.0f);
            }
        }
    }
}

// ---------------------------------------------------------------------------
extern "C" void kernel_launch(void* const* d_in, const int* in_sizes, int n_in,
                              void* d_out, int out_size, void* d_ws, size_t ws_size,
                              hipStream_t stream)
{
    (void)in_sizes; (void)n_in; (void)out_size; (void)ws_size;
    const float* fusion = (const float*)d_in[0];
    const float* rgb    = (const float*)d_in[1];
    const float* dsm    = (const float*)d_in[2];
    const float* bn1w = (const float*)d_in[3];
    const float* bn1b = (const float*)d_in[4];
    const float* bn1m = (const float*)d_in[5];
    const float* bn1v = (const float*)d_in[6];
    const float* bn2w = (const float*)d_in[7];
    const float* bn2b = (const float*)d_in[8];
    const float* bn2m = (const float*)d_in[9];
    const float* bn2v = (const float*)d_in[10];
    const float* kq1w = (const float*)d_in[11];
    const float* kq1b = (const float*)d_in[12];
    const float* kq2w = (const float*)d_in[13];
    const float* kq2b = (const float*)d_in[14];
    const float* vw   = (const float*)d_in[15];
    const float* vb   = (const float*)d_in[16];
    const float* outw = (const float*)d_in[17];
    const float* outb = (const float*)d_in[18];
    const float* bnlw = (const float*)d_in[19];
    const float* bnlb = (const float*)d_in[20];
    const float* bnlm = (const float*)d_in[21];
    const float* bnlv = (const float*)d_in[22];
    const float* gamma = (const float*)d_in[23];

    const size_t NKV = (size_t)4 * 2 * 4096 * 64;   // 2,097,152 elems per array
    bf16* K = (bf16*)d_ws;
    bf16* Q = K + NKV;
    bf16* V = Q + NKV;
    bf16* O = V + NKV;                               // (b, n, 128) bf16

    prep_kernel<<<256, 256, 0, stream>>>(fusion, rgb, dsm,
        bn1w, bn1b, bn1m, bn1v, bn2w, bn2b, bn2m, bn2v,
        kq1w, kq1b, kq2w, kq2b, vw, vb, K, Q, V);
    attn_kernel<<<512, 128, 0, stream>>>(K, Q, V, O);
    out_kernel<<<256, 256, 0, stream>>>(O, outw, outb,
        bnlw, bnlb, bnlm, bnlv, fusion, gamma, (float*)d_out);
}

// Round 2
// 203.047 us; speedup vs baseline: 1.1308x; 1.1308x over previous
//
#include <hip/hip_runtime.h>

typedef __bf16 bf16;
typedef __bf16 bf16x8 __attribute__((ext_vector_type(8)));
typedef float f32x2 __attribute__((ext_vector_type(2)));
typedef float f32x4 __attribute__((ext_vector_type(4)));
typedef float f32x16 __attribute__((ext_vector_type(16)));
typedef unsigned int u32;
typedef u32 u32x2 __attribute__((ext_vector_type(2)));
typedef u32 u32x4 __attribute__((ext_vector_type(4)));

#define MFMA16(A,B,C) __builtin_amdgcn_mfma_f32_16x16x32_bf16(A,B,C,0,0,0)
#define MFMA32(A,B,C) __builtin_amdgcn_mfma_f32_32x32x16_bf16(A,B,C,0,0,0)

#define ALPHA 0.18033688f          /* 0.125 * log2(e): folded into Q rows   */
#define LOG2E 1.44269504f

static __device__ __forceinline__ u32 cvt_pk_bf16(float lo, float hi) {
    u32 r;
    asm("v_cvt_pk_bf16_f32 %0, %1, %2" : "=v"(r) : "v"(lo), "v"(hi));
    return r;
}
static __device__ __forceinline__ void permlane32_swap(u32& a, u32& b) {
    asm("v_permlane32_swap_b32 %0, %1" : "+v"(a), "+v"(b));
}

// ---------------------------------------------------------------------------
// Kernel 0 (wprep): fold BN1/BN2 into kq weights+biases, bnl into out_w,
// Q-scale (0.125*log2e) into Q rows; convert all weights to bf16.
// grid 640 x 64: blocks 0-127 kq1 rows, 128-255 kq2, 256-383 v, 384-639 outw.
// ---------------------------------------------------------------------------
__global__ __launch_bounds__(64) void wprep_kernel(
    const float* __restrict__ kq1w, const float* __restrict__ kq1b,
    const float* __restrict__ bn1w, const float* __restrict__ bn1b,
    const float* __restrict__ bn1m, const float* __restrict__ bn1v,
    const float* __restrict__ kq2w, const float* __restrict__ kq2b,
    const float* __restrict__ bn2w, const float* __restrict__ bn2b,
    const float* __restrict__ bn2m, const float* __restrict__ bn2v,
    const float* __restrict__ vw,   const float* __restrict__ vb,
    const float* __restrict__ outw, const float* __restrict__ outb,
    const float* __restrict__ bnlw, const float* __restrict__ bnlb,
    const float* __restrict__ bnlm, const float* __restrict__ bnlv,
    bf16* __restrict__ Wk1, bf16* __restrict__ Wk2, bf16* __restrict__ Wv,
    bf16* __restrict__ Wo,
    float* __restrict__ B1, float* __restrict__ B2, float* __restrict__ Bv,
    float* __restrict__ Bo)
{
    const int blk = blockIdx.x, lane = threadIdx.x;
    if (blk < 384) {
        const int arr = blk >> 7, j = blk & 127;
        const float* W  = arr == 0 ? kq1w : arr == 1 ? kq2w : vw;
        const float* bs = arr == 0 ? kq1b : arr == 1 ? kq2b : vb;
        bf16*  Wd = arr == 0 ? Wk1 : arr == 1 ? Wk2 : Wv;
        float* Bd = arr == 0 ? B1  : arr == 1 ? B2  : Bv;
        const float scale = (arr < 2 && ((j >> 5) & 1)) ? ALPHA : 1.0f;
        const int c0 = lane * 4;
        f32x4 w4 = *(const f32x4*)(W + j * 256 + c0);
        f32x4 o4; float dot = 0.f;
        if (arr < 2) {
            const float* bw = arr ? bn2w : bn1w;
            const float* bb = arr ? bn2b : bn1b;
            const float* bm = arr ? bn2m : bn1m;
            const float* bv = arr ? bn2v : bn1v;
            f32x4 gw = *(const f32x4*)(bw + c0), gb = *(const f32x4*)(bb + c0);
            f32x4 gm = *(const f32x4*)(bm + c0), gv = *(const f32x4*)(bv + c0);
#pragma unroll
            for (int k = 0; k < 4; ++k) {
                float iv = gw[k] * rsqrtf(gv[k] + 1e-5f);
                float beta = gb[k] - gm[k] * iv;
                o4[k] = w4[k] * iv * scale;
                dot += w4[k] * beta;
            }
        } else {
#pragma unroll
            for (int k = 0; k < 4; ++k) o4[k] = w4[k];
        }
        u32x2 pk; pk[0] = cvt_pk_bf16(o4[0], o4[1]); pk[1] = cvt_pk_bf16(o4[2], o4[3]);
        *(u32x2*)(Wd + j * 256 + c0) = pk;
#pragma unroll
        for (int off = 32; off >= 1; off >>= 1) dot += __shfl_xor(dot, off);
        if (lane == 0) Bd[j] = (bs[j] + dot) * scale;
    } else {
        const int c = blk - 384;
        const float iv = bnlw[c] * rsqrtf(bnlv[c] + 1e-5f);
        const int k0 = lane * 2;
        f32x2 w2 = *(const f32x2*)(outw + c * 128 + k0);
        *(u32*)(Wo + c * 128 + k0) = cvt_pk_bf16(w2[0] * iv, w2[1] * iv);
        if (lane == 0) Bo[c] = outb[c] * iv + bnlb[c] - bnlm[c] * iv;
    }
}

// ---------------------------------------------------------------------------
// Kernel 1 (prep): D[j][n] = W' . X^T  (BN pre-folded, X converted on the fly)
// K,Q stored [bh][n][64] (b64 packed stores); V stored transposed Vt[bh][d][n].
// grid 512 (b x 128 n-tiles of 32) x 256 thr; wave: 16 n x 64 j.
// ---------------------------------------------------------------------------
template<int MODE>
static __device__ __forceinline__ void prep_mode(
    const float* __restrict__ X, const bf16* __restrict__ W,
    const float* __restrict__ B,
    int b, int n, int g, int l15, int cibase,
    bf16* __restrict__ K, bf16* __restrict__ Q, bf16* __restrict__ Vt)
{
    const f32x4 z4 = {0.f, 0.f, 0.f, 0.f};
    f32x4 acc[4] = {z4, z4, z4, z4};
    const float* Xb = X + b * 256 * 4096;
#pragma unroll
    for (int ks = 0; ks < 8; ++ks) {
        const int c0 = ks * 32 + g * 8;
        bf16x8 bfr;
#pragma unroll
        for (int jj = 0; jj < 8; ++jj) bfr[jj] = (bf16)Xb[(c0 + jj) * 4096 + n];
#pragma unroll
        for (int ci = 0; ci < 4; ++ci) {
            bf16x8 af = *(const bf16x8*)(W + ((cibase + ci) * 16 + l15) * 256 + c0);
            acc[ci] = MFMA16(af, bfr, acc[ci]);
        }
    }
#pragma unroll
    for (int ci = 0; ci < 4; ++ci) {
        const int cia = cibase + ci;
        const int j0 = cia * 16 + g * 4;
        const f32x4 bq = *(const f32x4*)(B + j0);
        float v0 = acc[ci][0] + bq[0], v1 = acc[ci][1] + bq[1];
        float v2 = acc[ci][2] + bq[2], v3 = acc[ci][3] + bq[3];
        if constexpr (MODE == 2) {
            const int head = cia >> 2;
            const int dbase = (cia & 3) * 16 + g * 4;
            bf16* vp = Vt + ((b * 2 + head) * 64 + dbase) * 4096 + n;
            vp[0] = (bf16)v0; vp[4096] = (bf16)v1; vp[8192] = (bf16)v2; vp[12288] = (bf16)v3;
        } else {
            const int seg = cia >> 1;          // 0:K h0  1:Q h0  2:K h1  3:Q h1
            const int head = seg >> 1;
            const int d0 = (cia & 1) * 16 + g * 4 + (MODE == 1 ? 32 : 0);
            bf16* dst = (seg & 1) ? Q : K;
            u32x2 pk; pk[0] = cvt_pk_bf16(v0, v1); pk[1] = cvt_pk_bf16(v2, v3);
            *(u32x2*)(dst + ((b * 2 + head) * 4096 + n) * 64 + d0) = pk;
        }
    }
}

__global__ __launch_bounds__(256) void prep_kernel(
    const float* __restrict__ rgb, const float* __restrict__ dsm,
    const float* __restrict__ fus,
    const bf16* __restrict__ Wk1, const bf16* __restrict__ Wk2,
    const bf16* __restrict__ Wv,
    const float* __restrict__ B1, const float* __restrict__ B2,
    const float* __restrict__ Bv,
    bf16* __restrict__ K, bf16* __restrict__ Q, bf16* __restrict__ Vt)
{
    const int id = blockIdx.x;
    const int b = id >> 7, nt = id & 127;
    const int t = threadIdx.x, lane = t & 63, w = t >> 6;
    const int l15 = lane & 15, g = lane >> 4;
    const int n = nt * 32 + (w & 1) * 16 + l15;
    const int cibase = (w >> 1) * 4;

    prep_mode<0>(rgb, Wk1, B1, b, n, g, l15, cibase, K, Q, Vt);
    prep_mode<1>(dsm, Wk2, B2, b, n, g, l15, cibase, K, Q, Vt);
    prep_mode<2>(fus, Wv,  Bv, b, n, g, l15, cibase, K, Q, Vt);
}

// ---------------------------------------------------------------------------
// Kernel 2 (attn): flash attention, split-K x4, zero LDS, zero barriers.
// Per wave: 32 q-rows, 16 key-blocks of 64. S^T = mfma32(Kfrag, Qfrag) keeps
// each q-row's P in-lane; exp2-domain softmax with defer-rescale (THR=5);
// P->bf16 via cvt_pk+permlane32_swap; O^T += mfma32(Vt frag (global b128), P).
// Partials (unnormalized O^T, m, l) to ws; combine kernel merges splits.
// ---------------------------------------------------------------------------
__global__ __launch_bounds__(256, 4) void attn_kernel(
    const bf16* __restrict__ K, const bf16* __restrict__ Q,
    const bf16* __restrict__ Vt,
    float* __restrict__ Opart, float* __restrict__ Ml)
{
    const int id = blockIdx.x;                    // 1024
    const int combo = (id & 7) + 8 * (id >> 8);   // XCD-grouped: 4 s/bh combos per XCD
    const int qt = (id >> 3) & 31;
    const int s = combo >> 3, bh = combo & 7;

    const int t = threadIdx.x, lane = t & 63, w = t >> 6;
    const int l31 = lane & 31, hi = lane >> 5;
    const int qrow = qt * 128 + w * 32 + l31;
    const int base = bh * 4096;

    bf16x8 qf[4];
    {
        const bf16* qp = Q + (base + qrow) * 64 + hi * 8;
#pragma unroll
        for (int ds = 0; ds < 4; ++ds) qf[ds] = *(const bf16x8*)(qp + ds * 16);
    }

    f32x16 ot0, ot1;
#pragma unroll
    for (int i = 0; i < 16; ++i) { ot0[i] = 0.f; ot1[i] = 0.f; }
    float m = -1e30f, lsum = 0.f;

    const bf16* Kb = K + (base + s * 1024) * 64;
    const bf16* Vb = Vt + bh * 64 * 4096 + s * 1024;

    for (int kb = 0; kb < 16; ++kb) {
        // ---- S^T ----
        float p[32];
#pragma unroll
        for (int kt = 0; kt < 2; ++kt) {
            f32x16 a;
#pragma unroll
            for (int i = 0; i < 16; ++i) a[i] = 0.f;
            const bf16* kp = Kb + (kb * 64 + kt * 32 + l31) * 64 + hi * 8;
#pragma unroll
            for (int ds = 0; ds < 4; ++ds) {
                bf16x8 kf = *(const bf16x8*)(kp + ds * 16);
                a = MFMA32(kf, qf[ds], a);
            }
#pragma unroll
            for (int r = 0; r < 16; ++r) p[kt * 16 + r] = a[r];
        }
        // ---- block max (tree + partner-lane merge) ----
        float t16[16];
#pragma unroll
        for (int i = 0; i < 16; ++i) t16[i] = fmaxf(p[i], p[i + 16]);
#pragma unroll
        for (int off = 8; off >= 1; off >>= 1)
#pragma unroll
            for (int i = 0; i < off; ++i) t16[i] = fmaxf(t16[i], t16[i + off]);
        const float bm = fmaxf(t16[0], __shfl_xor(t16[0], 32));
        // ---- defer-rescale (uniform branch) ----
        if (__any(bm > m + 5.f)) {
            const float mn = fmaxf(m, bm);
            const float cc = exp2f(m - mn);
            m = mn; lsum *= cc;
            ot0 = ot0 * cc; ot1 = ot1 * cc;
        }
        // ---- P = exp2(S - m); row sum ----
#pragma unroll
        for (int i = 0; i < 32; ++i) p[i] = exp2f(p[i] - m);
        float ps[16];
#pragma unroll
        for (int i = 0; i < 16; ++i) ps[i] = p[i] + p[i + 16];
#pragma unroll
        for (int off = 8; off >= 1; off >>= 1)
#pragma unroll
            for (int i = 0; i < off; ++i) ps[i] += ps[i + off];
        lsum += ps[0] + __shfl_xor(ps[0], 32);
        // ---- P -> bf16 B-fragments ----
        bf16x8 pa[4];
#pragma unroll
        for (int ks = 0; ks < 4; ++ks) {
            const int pb = 16 * (ks >> 1) + 8 * (ks & 1);
            u32 wa0 = cvt_pk_bf16(p[pb + 0], p[pb + 1]);
            u32 wa1 = cvt_pk_bf16(p[pb + 2], p[pb + 3]);
            u32 wb0 = cvt_pk_bf16(p[pb + 4], p[pb + 5]);
            u32 wb1 = cvt_pk_bf16(p[pb + 6], p[pb + 7]);
            permlane32_swap(wa0, wb0);
            permlane32_swap(wa1, wb1);
            u32x4 pk; pk[0] = wa0; pk[1] = wa1; pk[2] = wb0; pk[3] = wb1;
            pa[ks] = __builtin_bit_cast(bf16x8, pk);
        }
        // ---- O^T += V^T . P  (V^T fragments straight from global) ----
        {
            const bf16* vp = Vb + l31 * 4096 + kb * 64 + hi * 8;
#pragma unroll
            for (int ks = 0; ks < 4; ++ks) {
                bf16x8 vt = *(const bf16x8*)(vp + ks * 16);
                ot0 = MFMA32(vt, pa[ks], ot0);
            }
            vp += 32 * 4096;
#pragma unroll
            for (int ks = 0; ks < 4; ++ks) {
                bf16x8 vt = *(const bf16x8*)(vp + ks * 16);
                ot1 = MFMA32(vt, pa[ks], ot1);
            }
        }
    }

    // ---- store partials: O^T unnormalized + (m, lsum) ----
    const int row = base + qrow;
    float* op = Opart + (size_t)s * 2097152 + (size_t)row * 64;
#pragma unroll
    for (int a = 0; a < 4; ++a) {
        f32x4 v0, v1;
#pragma unroll
        for (int rr = 0; rr < 4; ++rr) { v0[rr] = ot0[a * 4 + rr]; v1[rr] = ot1[a * 4 + rr]; }
        *(f32x4*)(op + 8 * a + 4 * hi)      = v0;
        *(f32x4*)(op + 32 + 8 * a + 4 * hi) = v1;
    }
    f32x2 ml; ml[0] = m; ml[1] = lsum;
    *(f32x2*)(Ml + ((size_t)s * 32768 + row) * 2) = ml;
}

// ---------------------------------------------------------------------------
// Kernel 3 (combine): merge 4 split-K partials -> O[b][n][128] bf16.
// thread = (row, d-pair). grid 4096 x 256.
// ---------------------------------------------------------------------------
__global__ __launch_bounds__(256) void combine_kernel(
    const float* __restrict__ Opart, const float* __restrict__ Ml,
    bf16* __restrict__ O)
{
    const int idx = blockIdx.x * 256 + threadIdx.x;
    const int row = idx >> 5, dp = idx & 31;
    float mm[4], ll[4];
#pragma unroll
    for (int s = 0; s < 4; ++s) {
        f32x2 ml = *(const f32x2*)(Ml + ((size_t)s * 32768 + row) * 2);
        mm[s] = ml[0]; ll[s] = ml[1];
    }
    float M = fmaxf(fmaxf(mm[0], mm[1]), fmaxf(mm[2], mm[3]));
    float L = 0.f; f32x2 acc; acc[0] = 0.f; acc[1] = 0.f;
#pragma unroll
    for (int s = 0; s < 4; ++s) {
        const float ws = exp2f(mm[s] - M);
        L += ws * ll[s];
        f32x2 o2 = *(const f32x2*)(Opart + (size_t)s * 2097152 + (size_t)row * 64 + dp * 2);
        acc[0] += ws * o2[0]; acc[1] += ws * o2[1];
    }
    const float rl = 1.0f / L;
    const int bh = row >> 12, n = row & 4095, b = bh >> 1, h = bh & 1;
    *(u32*)(O + ((size_t)(b * 4096 + n)) * 128 + h * 64 + dp * 2) =
        cvt_pk_bf16(acc[0] * rl, acc[1] * rl);
}

// ---------------------------------------------------------------------------
// Kernel 4 (out): out = sigmoid(Wo'.O^T + Bo') * fus * gamma + fus
// (bnl pre-folded into Wo'/Bo'). D[c][n]; B-frags = contiguous b128 from O.
// grid 512 (b x 128 n-tiles of 32) x 256 thr; wave: 16 n x 128 c.
// ---------------------------------------------------------------------------
__global__ __launch_bounds__(256) void out_kernel(
    const bf16* __restrict__ O, const bf16* __restrict__ Wo,
    const float* __restrict__ Bo, const float* __restrict__ fus,
    const float* __restrict__ gamma, float* __restrict__ out)
{
    const int id = blockIdx.x;
    const int b = id >> 7, nt = id & 127;
    const int t = threadIdx.x, lane = t & 63, w = t >> 6;
    const int l15 = lane & 15, g = lane >> 4;
    const int n = nt * 32 + (w & 1) * 16 + l15;
    const int cibase = (w >> 1) * 8;

    const f32x4 z4 = {0.f, 0.f, 0.f, 0.f};
    f32x4 acc[8] = {z4, z4, z4, z4, z4, z4, z4, z4};
    const bf16* Op = O + ((size_t)(b * 4096 + n)) * 128;
#pragma unroll
    for (int ks = 0; ks < 4; ++ks) {
        const int k0 = ks * 32 + g * 8;
        bf16x8 bfr = *(const bf16x8*)(Op + k0);
#pragma unroll
        for (int ci = 0; ci < 8; ++ci) {
            bf16x8 af = *(const bf16x8*)(Wo + ((cibase + ci) * 16 + l15) * 128 + k0);
            acc[ci] = MFMA16(af, bfr, acc[ci]);
        }
    }
    const float gam = gamma[0];
#pragma unroll
    for (int ci = 0; ci < 8; ++ci) {
        const int c0 = (cibase + ci) * 16 + g * 4;
        const f32x4 bo = *(const f32x4*)(Bo + c0);
#pragma unroll
        for (int r = 0; r < 4; ++r) {
            const int c = c0 + r;
            const size_t off = ((size_t)(b * 256 + c)) * 4096 + n;
            const float v = acc[ci][r] + bo[r];
            const float sg = 1.0f / (1.0f + exp2f(-v * LOG2E));
            out[off] = fus[off] * fmaf(sg, gam, 1.0f);
        }
    }
}

// ---------------------------------------------------------------------------
extern "C" void kernel_launch(void* const* d_in, const int* in_sizes, int n_in,
                              void* d_out, int out_size, void* d_ws, size_t ws_size,
                              hipStream_t stream)
{
    (void)in_sizes; (void)n_in; (void)out_size; (void)ws_size;
    const float* fusion = (const float*)d_in[0];
    const float* rgb    = (const float*)d_in[1];
    const float* dsm    = (const float*)d_in[2];
    const float* bn1w = (const float*)d_in[3];
    const float* bn1b = (const float*)d_in[4];
    const float* bn1m = (const float*)d_in[5];
    const float* bn1v = (const float*)d_in[6];
    const float* bn2w = (const float*)d_in[7];
    const float* bn2b = (const float*)d_in[8];
    const float* bn2m = (const float*)d_in[9];
    const float* bn2v = (const float*)d_in[10];
    const float* kq1w = (const float*)d_in[11];
    const float* kq1b = (const float*)d_in[12];
    const float* kq2w = (const float*)d_in[13];
    const float* kq2b = (const float*)d_in[14];
    const float* vw   = (const float*)d_in[15];
    const float* vb   = (const float*)d_in[16];
    const float* outw = (const float*)d_in[17];
    const float* outb = (const float*)d_in[18];
    const float* bnlw = (const float*)d_in[19];
    const float* bnlb = (const float*)d_in[20];
    const float* bnlm = (const float*)d_in[21];
    const float* bnlv = (const float*)d_in[22];
    const float* gamma = (const float*)d_in[23];

    char* ws = (char*)d_ws;
    size_t off = 0;
    auto alloc = [&](size_t bytes) { char* p = ws + off; off = (off + bytes + 255) & ~(size_t)255; return p; };
    bf16* Wk1 = (bf16*)alloc(128 * 256 * 2);
    bf16* Wk2 = (bf16*)alloc(128 * 256 * 2);
    bf16* Wv  = (bf16*)alloc(128 * 256 * 2);
    bf16* Wo  = (bf16*)alloc(256 * 128 * 2);
    float* B1 = (float*)alloc(128 * 4);
    float* B2 = (float*)alloc(128 * 4);
    float* Bv = (float*)alloc(128 * 4);
    float* Bo = (float*)alloc(256 * 4);
    bf16* K  = (bf16*)alloc((size_t)8 * 4096 * 64 * 2);
    bf16* Q  = (bf16*)alloc((size_t)8 * 4096 * 64 * 2);
    bf16* Vt = (bf16*)alloc((size_t)8 * 64 * 4096 * 2);
    bf16* O  = (bf16*)alloc((size_t)4 * 4096 * 128 * 2);
    float* Opart = (float*)alloc((size_t)4 * 2097152 * 4);
    float* Ml    = (float*)alloc((size_t)4 * 32768 * 2 * 4);

    wprep_kernel<<<640, 64, 0, stream>>>(
        kq1w, kq1b, bn1w, bn1b, bn1m, bn1v,
        kq2w, kq2b, bn2w, bn2b, bn2m, bn2v,
        vw, vb, outw, outb, bnlw, bnlb, bnlm, bnlv,
        Wk1, Wk2, Wv, Wo, B1, B2, Bv, Bo);
    prep_kernel<<<512, 256, 0, stream>>>(rgb, dsm, fusion,
        Wk1, Wk2, Wv, B1, B2, Bv, K, Q, Vt);
    attn_kernel<<<1024, 256, 0, stream>>>(K, Q, Vt, Opart, Ml);
    combine_kernel<<<4096, 256, 0, stream>>>(Opart, Ml, O);
    out_kernel<<<512, 256, 0, stream>>>(O, Wo, Bo, fusion, gamma, (float*)d_out);
}